// Round 9
// baseline (160.954 us; speedup 1.0000x reference)
//
#include <hip/hip_runtime.h>
#include <hip/hip_bf16.h>

#define NB 32
#define NP 4096
#define NM 12
#define NW 9
#define NC 64          // IN_C == OUT_C == 64
#define PN_PAD 4097
#define KDIM (NW * NC)     // 576
#define KSTEPS (KDIM / 32) // 18
#define AROW 584           // 576 + 8 pad shorts (16B-aligned rows)

#define WSW_BYTES (KDIM * NC * 2)            // 73728 B  bf16 swizzled weights
#define W2_OFFSET WSW_BYTES
#define W2_BYTES (NP * NM * 12 * 4)          // 2359296 B  w2d
#define XB_OFFSET (W2_OFFSET + W2_BYTES)     // 2433024 (128B-aligned)
#define XB_BYTES (NB * PN_PAD * NC * 2)      // 16781312 B  bf16 x
#define WS_NEED ((size_t)XB_OFFSET + XB_BYTES)

typedef __attribute__((ext_vector_type(8))) short short8;
typedef __attribute__((ext_vector_type(4))) float float4v;

__device__ __forceinline__ unsigned short f32_to_bf16(float f) {
    union { float f; unsigned u; } v; v.f = f;
    unsigned r = v.u + 0x7FFFu + ((v.u >> 16) & 1u);  // RNE
    return (unsigned short)(r >> 16);
}

// Pack float4 -> 4 bf16 (round via +0x8000, take high 16 bits)
__device__ __forceinline__ uint2 pack_bf16x4(float4v v) {
    union { float f; unsigned u; } a0, a1, a2, a3;
    a0.f = v[0]; a1.f = v[1]; a2.f = v[2]; a3.f = v[3];
    unsigned u0 = a0.u + 0x8000u, u1 = a1.u + 0x8000u;
    unsigned u2 = a2.u + 0x8000u, u3 = a3.u + 0x8000u;
    uint2 r;
    r.x = __builtin_amdgcn_perm(u1, u0, 0x07060302u);
    r.y = __builtin_amdgcn_perm(u3, u2, 0x07060302u);
    return r;
}

// 4 packed bf16 -> float4 (bf16->f32 is a 16-bit left shift)
__device__ __forceinline__ float4v bf16x4_to_f32(uint2 u) {
    union { unsigned u; float f; } c0, c1, c2, c3;
    c0.u = u.x << 16; c1.u = u.x & 0xFFFF0000u;
    c2.u = u.y << 16; c3.u = u.y & 0xFFFF0000u;
    return (float4v){c0.f, c1.f, c2.f, c3.f};
}

// Prep: (a) swizzle weights fp32 -> bf16 in MFMA B-fragment order;
//       (b) w2d[(p*12+m)*12 + w] = ww[p,m,w] * mask[p,m]
__global__ void prep(const float* __restrict__ w,
                     const float* __restrict__ ww,
                     const float* __restrict__ mask,
                     unsigned short* __restrict__ wsw,
                     float* __restrict__ w2d) {
    int idx = blockIdx.x * 256 + threadIdx.x;
    if (idx < KDIM * NC) {
        int j    = idx & 7;
        int lane = (idx >> 3) & 63;
        int nt   = (idx >> 9) & 3;
        int ks   = idx >> 11;
        int k = ks * 32 + ((lane >> 4) * 8) + j;   // k = w*64 + i
        int n = nt * 16 + (lane & 15);             // n = o
        int wi = k >> 6;
        int ii = k & 63;
        wsw[idx] = f32_to_bf16(w[wi * (NC * NC) + n * NC + ii]);
    }
    if (idx < NP * NM * NW) {
        int wq = idx % NW;
        int pm = idx / NW;       // p*12 + m
        w2d[pm * 12 + wq] = ww[idx] * mask[pm];
    }
}

// Convert x (fp32) -> bf16 rows in workspace.
__global__ void prep_x(const float* __restrict__ x,
                       unsigned short* __restrict__ xb) {
    int idx = blockIdx.x * 256 + threadIdx.x;
    const int n4 = NB * PN_PAD * NC / 4;  // 2097664
    if (idx < n4) {
        const float4v* x4 = (const float4v*)x;
        ((uint2*)xb)[idx] = pack_bf16x4(x4[idx]);
    }
}

// XCD-locality blocking: block = (pg, bg) with bg = blockIdx & 7.
// Round-robin dispatch puts all blocks of one bg on one XCD, whose 4-b slice
// of xb (2.1 MB) becomes L2-resident: gather latency L3(~600cy) -> L2(~200cy)
// and FETCH collapses toward one cold read of xb.
// A-tile rows r = pl*4 + bl (8 p's x 4 b's = 32 rows x 576). Within a wave
// pl == wid, so nid/w2 reads stay wave-uniform (scalar). Phase 2 unchanged.
__global__ __launch_bounds__(512)
void conv_main_bf16(const unsigned short* __restrict__ xb,  // (32, 4097, 64) bf16
                    const unsigned short* __restrict__ wsw,
                    const float* __restrict__ bias,
                    const float* __restrict__ w2d,
                    const int* __restrict__ nid,
                    float* __restrict__ out) {
    __shared__ __align__(16) unsigned short A[NB * AROW];

    const int bg = blockIdx.x & 7;    // b-group -> XCD (heuristic, perf-only)
    const int pg = blockIdx.x >> 3;   // 0..511, 8 p's per block
    const int tid = threadIdx.x;

    // ---- Phase 1 ----
    {
        const int i4 = tid & 15;      // 4-channel group within the 64-ch row
        const int r  = tid >> 4;      // A-tile row 0..31
        const int pl = r >> 2;        // 0..7  (== wid within a wave)
        const int bl = r & 3;         // 0..3  (== lane quad)
        const int p  = pg * 8 + pl;
        const int b  = bg * 4 + bl;

        const uint2* xb2 = (const uint2*)xb;   // row = 16 uint2 (128 B)
        const float* w2p = w2d + p * (NM * 12);
        const int* nidp = nid + p * NM;

        int nm[NM];
        #pragma unroll
        for (int m = 0; m < NM; ++m) nm[m] = nidp[m];  // wave-uniform -> SGPRs

        uint2 xv[NM];
        #pragma unroll
        for (int m = 0; m < NM; ++m)
            xv[m] = xb2[(b * PN_PAD + nm[m]) * 16 + i4];

        float4v acc[NW];
        #pragma unroll
        for (int w = 0; w < NW; ++w) acc[w] = (float4v){0.f, 0.f, 0.f, 0.f};

        #pragma unroll
        for (int m = 0; m < NM; ++m) {
            const float4v xf = bf16x4_to_f32(xv[m]);
            #pragma unroll
            for (int w = 0; w < NW; ++w)
                acc[w] += w2p[m * 12 + w] * xf;
        }

        #pragma unroll
        for (int w = 0; w < NW; ++w)
            *(uint2*)&A[r * AROW + w * 64 + i4 * 4] = pack_bf16x4(acc[w]);
    }
    __syncthreads();

    // ---- Phase 2: C[32x64] = A(32x576) * B(576x64), mfma 16x16x32 bf16 ----
    {
        const int lane = tid & 63;
        const int wid  = tid >> 6;
        const int nt   = wid & 3;
        const int mt   = wid >> 2;
        const int quad = lane >> 4;
        const int l15  = lane & 15;

        float4v acc = {0.f, 0.f, 0.f, 0.f};
        const short8* Bfrags = (const short8*)wsw;
        const int arow = mt * 16 + l15;

        #pragma unroll
        for (int ks = 0; ks < KSTEPS; ++ks) {
            short8 bfrag = Bfrags[(ks * 4 + nt) * 64 + lane];
            const short8 a = *(const short8*)&A[arow * AROW + ks * 32 + quad * 8];
            acc = __builtin_amdgcn_mfma_f32_16x16x32_bf16(a, bfrag, acc, 0, 0, 0);
        }

        const int o = nt * 16 + l15;
        const float bv = bias[o];
        #pragma unroll
        for (int reg = 0; reg < 4; ++reg) {
            const int rr = mt * 16 + quad * 4 + reg;  // A-tile row
            const int p  = pg * 8 + (rr >> 2);
            const int b  = bg * 4 + (rr & 3);
            out[(b * NP + p) * NC + o] = acc[reg] + bv;
        }
    }
}

// Fallback (fp32 gather, block-per-p) if workspace is too small for xb.
__global__ __launch_bounds__(512)
void conv_main_fp32(const float* __restrict__ x,
                    const unsigned short* __restrict__ wsw,
                    const float* __restrict__ bias,
                    const float* __restrict__ w2d,
                    const int* __restrict__ nid,
                    float* __restrict__ out) {
    __shared__ __align__(16) unsigned short A[NB * AROW];
    const int p = blockIdx.x;
    const int tid = threadIdx.x;
    {
        const int i4 = tid & 15;
        const int b  = tid >> 4;
        const float4v* x4 = (const float4v*)x;
        const float* w2p = w2d + p * (NM * 12);
        const int* nidp = nid + p * NM;
        int nm[NM];
        #pragma unroll
        for (int m = 0; m < NM; ++m) nm[m] = nidp[m];
        float4v xv[NM];
        #pragma unroll
        for (int m = 0; m < NM; ++m)
            xv[m] = x4[(b * PN_PAD + nm[m]) * 16 + i4];
        float4v acc[NW];
        #pragma unroll
        for (int w = 0; w < NW; ++w) acc[w] = (float4v){0.f, 0.f, 0.f, 0.f};
        #pragma unroll
        for (int m = 0; m < NM; ++m) {
            #pragma unroll
            for (int w = 0; w < NW; ++w)
                acc[w] += w2p[m * 12 + w] * xv[m];
        }
        #pragma unroll
        for (int w = 0; w < NW; ++w)
            *(uint2*)&A[b * AROW + w * 64 + i4 * 4] = pack_bf16x4(acc[w]);
    }
    __syncthreads();
    {
        const int lane = tid & 63;
        const int wid  = tid >> 6;
        const int nt   = wid & 3;
        const int mt   = wid >> 2;
        const int quad = lane >> 4;
        const int l15  = lane & 15;
        float4v acc = {0.f, 0.f, 0.f, 0.f};
        const short8* Bfrags = (const short8*)wsw;
        const int arow = mt * 16 + l15;
        #pragma unroll
        for (int ks = 0; ks < KSTEPS; ++ks) {
            short8 bfrag = Bfrags[(ks * 4 + nt) * 64 + lane];
            const short8 a = *(const short8*)&A[arow * AROW + ks * 32 + quad * 8];
            acc = __builtin_amdgcn_mfma_f32_16x16x32_bf16(a, bfrag, acc, 0, 0, 0);
        }
        const int o = nt * 16 + l15;
        const float bv = bias[o];
        #pragma unroll
        for (int reg = 0; reg < 4; ++reg) {
            const int b = mt * 16 + quad * 4 + reg;
            out[(b * NP + p) * NC + o] = acc[reg] + bv;
        }
    }
}

extern "C" void kernel_launch(void* const* d_in, const int* in_sizes, int n_in,
                              void* d_out, int out_size, void* d_ws, size_t ws_size,
                              hipStream_t stream) {
    const float* x    = (const float*)d_in[0];
    const float* w    = (const float*)d_in[1];
    const float* bias = (const float*)d_in[2];
    const float* ww   = (const float*)d_in[3];
    const int*   nid  = (const int*)d_in[4];
    const float* mask = (const float*)d_in[5];
    float* out = (float*)d_out;
    unsigned short* wsw = (unsigned short*)d_ws;
    float* w2d = (float*)((char*)d_ws + W2_OFFSET);
    unsigned short* xb = (unsigned short*)((char*)d_ws + XB_OFFSET);

    const int prep_elems = NP * NM * NW;  // 442368 covers both prep jobs
    hipLaunchKernelGGL(prep, dim3((prep_elems + 255) / 256), dim3(256), 0, stream,
                       w, ww, mask, wsw, w2d);
    if (ws_size >= WS_NEED) {
        const int n4 = NB * PN_PAD * NC / 4;  // 2097664
        hipLaunchKernelGGL(prep_x, dim3((n4 + 255) / 256), dim3(256), 0, stream,
                           x, xb);
        hipLaunchKernelGGL(conv_main_bf16, dim3(NP), dim3(512), 0, stream,
                           xb, wsw, bias, w2d, nid, out);
    } else {
        hipLaunchKernelGGL(conv_main_fp32, dim3(NP), dim3(512), 0, stream,
                           x, wsw, bias, w2d, nid, out);
    }
}

// Round 10
// 152.186 us; speedup vs baseline: 1.0576x; 1.0576x over previous
//
#include <hip/hip_runtime.h>
#include <hip/hip_bf16.h>

#define NB 32
#define NP 4096
#define NM 12
#define NW 9
#define NC 64          // IN_C == OUT_C == 64
#define PN_PAD 4097
#define KDIM (NW * NC)     // 576
#define KSTEPS (KDIM / 32) // 18
#define AROW 584           // 576 + 8 pad shorts (16B-aligned rows)
#define SSEG 6144          // per-wave stage bytes (4 b x 12 m x 128 B)

#define WSW_BYTES (KDIM * NC * 2)            // 73728 B  bf16 swizzled weights
#define W2_OFFSET WSW_BYTES
#define W2_BYTES (NP * NM * 12 * 4)          // 2359296 B  w2d
#define XB_OFFSET (W2_OFFSET + W2_BYTES)     // 2433024 (128B-aligned)
#define XB_BYTES (NB * PN_PAD * NC * 2)      // 16781312 B  bf16 x
#define WS_NEED ((size_t)XB_OFFSET + XB_BYTES)

typedef __attribute__((ext_vector_type(8))) short short8;
typedef __attribute__((ext_vector_type(4))) float float4v;

// async global->LDS DMA, 16 B per lane; LDS dest = wave-uniform base + lane*16
#define GLD_LDS16(g, l) __builtin_amdgcn_global_load_lds( \
    (const __attribute__((address_space(1))) unsigned int*)(g), \
    (__attribute__((address_space(3))) unsigned int*)(l), 16, 0, 0)

__device__ __forceinline__ unsigned short f32_to_bf16(float f) {
    union { float f; unsigned u; } v; v.f = f;
    unsigned r = v.u + 0x7FFFu + ((v.u >> 16) & 1u);  // RNE
    return (unsigned short)(r >> 16);
}

// Pack float4 -> 4 bf16 (round via +0x8000, take high 16 bits)
__device__ __forceinline__ uint2 pack_bf16x4(float4v v) {
    union { float f; unsigned u; } a0, a1, a2, a3;
    a0.f = v[0]; a1.f = v[1]; a2.f = v[2]; a3.f = v[3];
    unsigned u0 = a0.u + 0x8000u, u1 = a1.u + 0x8000u;
    unsigned u2 = a2.u + 0x8000u, u3 = a3.u + 0x8000u;
    uint2 r;
    r.x = __builtin_amdgcn_perm(u1, u0, 0x07060302u);
    r.y = __builtin_amdgcn_perm(u3, u2, 0x07060302u);
    return r;
}

// 4 packed bf16 -> float4 (bf16->f32 is a 16-bit left shift)
__device__ __forceinline__ float4v bf16x4_to_f32(uint2 u) {
    union { unsigned u; float f; } c0, c1, c2, c3;
    c0.u = u.x << 16; c1.u = u.x & 0xFFFF0000u;
    c2.u = u.y << 16; c3.u = u.y & 0xFFFF0000u;
    return (float4v){c0.f, c1.f, c2.f, c3.f};
}

// Prep: (a) swizzle weights fp32 -> bf16 in MFMA B-fragment order;
//       (b) w2d[(p*12+m)*12 + w] = ww[p,m,w] * mask[p,m]
__global__ void prep(const float* __restrict__ w,
                     const float* __restrict__ ww,
                     const float* __restrict__ mask,
                     unsigned short* __restrict__ wsw,
                     float* __restrict__ w2d) {
    int idx = blockIdx.x * 256 + threadIdx.x;
    if (idx < KDIM * NC) {
        int j    = idx & 7;
        int lane = (idx >> 3) & 63;
        int nt   = (idx >> 9) & 3;
        int ks   = idx >> 11;
        int k = ks * 32 + ((lane >> 4) * 8) + j;   // k = w*64 + i
        int n = nt * 16 + (lane & 15);             // n = o
        int wi = k >> 6;
        int ii = k & 63;
        wsw[idx] = f32_to_bf16(w[wi * (NC * NC) + n * NC + ii]);
    }
    if (idx < NP * NM * NW) {
        int wq = idx % NW;
        int pm = idx / NW;       // p*12 + m
        w2d[pm * 12 + wq] = ww[idx] * mask[pm];
    }
}

// Convert x (fp32) -> bf16 rows in workspace.
__global__ void prep_x(const float* __restrict__ x,
                       unsigned short* __restrict__ xb) {
    int idx = blockIdx.x * 256 + threadIdx.x;
    const int n4 = NB * PN_PAD * NC / 4;  // 2097664
    if (idx < n4) {
        const float4v* x4 = (const float4v*)x;
        ((uint2*)xb)[idx] = pack_bf16x4(x4[idx]);
    }
}

// One block (512 threads) per p.
// Gather via PER-WAVE DMA staging, no block barrier in the load path:
// wave wid stages its 48 row-segments (b = wid*4..wid*4+3, m = 0..11, 128 B
// each) with 6 global_load_lds dwordx4 into its private 6 KB LDS region,
// waits ITS OWN vmcnt(0), then consumes. One latency exposure per wave
// (vs 12 serialized register chains); waves overlap freely.
// Stage layout: seg s of instr j at wid*SSEG + j*1024 + s*128, where
// s = (m&1)*4 + bq, j = m>>1  (m = 2j + (s>>2), bq = s&3).
// A-tile (37376 B) aliases the 48 KB stage after a barrier. Phase 2 as R7.
__global__ __launch_bounds__(512)
void conv_main_bf16(const unsigned short* __restrict__ xb,  // (32, 4097, 64) bf16
                    const unsigned short* __restrict__ wsw,
                    const float* __restrict__ bias,
                    const float* __restrict__ w2d,
                    const int* __restrict__ nid,
                    float* __restrict__ out) {
    __shared__ __align__(16) unsigned char S[8 * SSEG];  // 49152 B

    const int p = blockIdx.x;
    const int tid = threadIdx.x;
    const int lane = tid & 63;
    const int wid  = tid >> 6;

    const float* w2p = w2d + p * (NM * 12);
    const int* nidp = nid + p * NM;

    int nm[NM];
    #pragma unroll
    for (int m = 0; m < NM; ++m) nm[m] = nidp[m];  // wave-uniform -> SGPRs

    // ---- DMA issue: 6 fire-and-forget instructions per wave ----
    {
        const int msel = lane >> 5;           // 0/1: which of the 2 m's
        const int bq   = (lane >> 3) & 3;     // b-quad within wave
        const int b    = wid * 4 + bq;
        const int ch16 = (lane & 7) * 16;     // byte offset within 128 B row
        #pragma unroll
        for (int j = 0; j < 6; ++j) {
            const int mr = msel ? nm[2 * j + 1] : nm[2 * j];
            const unsigned char* gsrc = (const unsigned char*)xb
                + ((size_t)(b * PN_PAD + mr)) * 128 + ch16;
            unsigned char* ldst = S + wid * SSEG + j * 1024;  // uniform base
            GLD_LDS16(gsrc, ldst);
        }
    }

    // Wait for THIS wave's DMAs only; "memory" clobber = compiler fence so
    // the ds_reads below cannot be hoisted above the wait.
    asm volatile("s_waitcnt vmcnt(0)" ::: "memory");

    // ---- consume: 12 ds_read_b64 (conflict-free) + 108 FMAs per thread ----
    const int i4 = tid & 15;      // 4-channel group
    const int bq = (lane >> 4);   // 0..3
    float4v acc[NW];
    #pragma unroll
    for (int w = 0; w < NW; ++w) acc[w] = (float4v){0.f, 0.f, 0.f, 0.f};

    #pragma unroll
    for (int m = 0; m < NM; ++m) {
        const uint2 xv = *(const uint2*)(S + wid * SSEG + (m >> 1) * 1024
                                         + ((m & 1) * 4 + bq) * 128 + i4 * 8);
        const float4v xf = bf16x4_to_f32(xv);
        #pragma unroll
        for (int w = 0; w < NW; ++w)
            acc[w] += w2p[m * 12 + w] * xf;
    }
    __syncthreads();  // all waves done consuming before A overwrites stages

    // ---- write bf16 A-tile (aliases stage region) ----
    unsigned short* A = (unsigned short*)S;
    const int b = tid >> 4;       // 0..31 == wid*4 + bq
    #pragma unroll
    for (int w = 0; w < NW; ++w)
        *(uint2*)&A[b * AROW + w * 64 + i4 * 4] = pack_bf16x4(acc[w]);
    __syncthreads();

    // ---- Phase 2: C[32x64] = A(32x576) * B(576x64), mfma 16x16x32 bf16 ----
    {
        const int nt   = wid & 3;
        const int mt   = wid >> 2;
        const int quad = lane >> 4;
        const int l15  = lane & 15;

        float4v cacc = {0.f, 0.f, 0.f, 0.f};
        const short8* Bfrags = (const short8*)wsw;
        const int arow = mt * 16 + l15;

        #pragma unroll
        for (int ks = 0; ks < KSTEPS; ++ks) {
            short8 bfrag = Bfrags[(ks * 4 + nt) * 64 + lane];
            const short8 a = *(const short8*)&A[arow * AROW + ks * 32 + quad * 8];
            cacc = __builtin_amdgcn_mfma_f32_16x16x32_bf16(a, bfrag, cacc, 0, 0, 0);
        }

        const int o = nt * 16 + l15;
        const float bv = bias[o];
        #pragma unroll
        for (int reg = 0; reg < 4; ++reg) {
            const int bb = mt * 16 + quad * 4 + reg;
            out[(bb * NP + p) * NC + o] = cacc[reg] + bv;
        }
    }
}

// Fallback (fp32 gather, R4/R7 structure) if workspace is too small for xb.
__global__ __launch_bounds__(512)
void conv_main_fp32(const float* __restrict__ x,
                    const unsigned short* __restrict__ wsw,
                    const float* __restrict__ bias,
                    const float* __restrict__ w2d,
                    const int* __restrict__ nid,
                    float* __restrict__ out) {
    __shared__ __align__(16) unsigned short A[NB * AROW];
    const int p = blockIdx.x;
    const int tid = threadIdx.x;
    {
        const int i4 = tid & 15;
        const int b  = tid >> 4;
        const float4v* x4 = (const float4v*)x;
        const float* w2p = w2d + p * (NM * 12);
        const int* nidp = nid + p * NM;
        int nm[NM];
        #pragma unroll
        for (int m = 0; m < NM; ++m) nm[m] = nidp[m];
        float4v xv[NM];
        #pragma unroll
        for (int m = 0; m < NM; ++m)
            xv[m] = x4[(b * PN_PAD + nm[m]) * 16 + i4];
        float4v acc[NW];
        #pragma unroll
        for (int w = 0; w < NW; ++w) acc[w] = (float4v){0.f, 0.f, 0.f, 0.f};
        #pragma unroll
        for (int m = 0; m < NM; ++m) {
            #pragma unroll
            for (int w = 0; w < NW; ++w)
                acc[w] += w2p[m * 12 + w] * xv[m];
        }
        #pragma unroll
        for (int w = 0; w < NW; ++w)
            *(uint2*)&A[b * AROW + w * 64 + i4 * 4] = pack_bf16x4(acc[w]);
    }
    __syncthreads();
    {
        const int lane = tid & 63;
        const int wid  = tid >> 6;
        const int nt   = wid & 3;
        const int mt   = wid >> 2;
        const int quad = lane >> 4;
        const int l15  = lane & 15;
        float4v acc = {0.f, 0.f, 0.f, 0.f};
        const short8* Bfrags = (const short8*)wsw;
        const int arow = mt * 16 + l15;
        #pragma unroll
        for (int ks = 0; ks < KSTEPS; ++ks) {
            short8 bfrag = Bfrags[(ks * 4 + nt) * 64 + lane];
            const short8 a = *(const short8*)&A[arow * AROW + ks * 32 + quad * 8];
            acc = __builtin_amdgcn_mfma_f32_16x16x32_bf16(a, bfrag, acc, 0, 0, 0);
        }
        const int o = nt * 16 + l15;
        const float bv = bias[o];
        #pragma unroll
        for (int reg = 0; reg < 4; ++reg) {
            const int b = mt * 16 + quad * 4 + reg;
            out[(b * NP + p) * NC + o] = acc[reg] + bv;
        }
    }
}

extern "C" void kernel_launch(void* const* d_in, const int* in_sizes, int n_in,
                              void* d_out, int out_size, void* d_ws, size_t ws_size,
                              hipStream_t stream) {
    const float* x    = (const float*)d_in[0];
    const float* w    = (const float*)d_in[1];
    const float* bias = (const float*)d_in[2];
    const float* ww   = (const float*)d_in[3];
    const int*   nid  = (const int*)d_in[4];
    const float* mask = (const float*)d_in[5];
    float* out = (float*)d_out;
    unsigned short* wsw = (unsigned short*)d_ws;
    float* w2d = (float*)((char*)d_ws + W2_OFFSET);
    unsigned short* xb = (unsigned short*)((char*)d_ws + XB_OFFSET);

    const int prep_elems = NP * NM * NW;  // 442368 covers both prep jobs
    hipLaunchKernelGGL(prep, dim3((prep_elems + 255) / 256), dim3(256), 0, stream,
                       w, ww, mask, wsw, w2d);
    if (ws_size >= WS_NEED) {
        const int n4 = NB * PN_PAD * NC / 4;  // 2097664
        hipLaunchKernelGGL(prep_x, dim3((n4 + 255) / 256), dim3(256), 0, stream,
                           x, xb);
        hipLaunchKernelGGL(conv_main_bf16, dim3(NP), dim3(512), 0, stream,
                           xb, wsw, bias, w2d, nid, out);
    } else {
        hipLaunchKernelGGL(conv_main_fp32, dim3(NP), dim3(512), 0, stream,
                           x, wsw, bias, w2d, nid, out);
    }
}